// Round 1
// baseline (121.487 us; speedup 1.0000x reference)
//
#include <hip/hip_runtime.h>
#include <stdint.h>

// Problem constants (fixed by the reference)
#define NB    32768   // batch
#define NS    16      // states per element
#define SS    32      // state size (K of stage 1)
#define ENCD  64      // encoder width
#define HIDD  128     // hidden width
#define OUTD  8       // output logits
#define BT    32      // batch elements per block
#define THREADS 256   // 4 waves

typedef short bf16x8 __attribute__((ext_vector_type(8)));  // 8 bf16 in 4 VGPRs
typedef float f32x4  __attribute__((ext_vector_type(4)));

#define MFMA(a, b, c) __builtin_amdgcn_mfma_f32_16x16x32_bf16((a), (b), (c), 0, 0, 0)

// float -> bf16 bits, round-to-nearest-even
__device__ __forceinline__ short bf16_bits(float x) {
  union { float f; uint32_t u; } v; v.f = x;
  uint32_t u = v.u;
  uint32_t r = (u + 0x7FFFu + ((u >> 16) & 1u)) >> 16;
  return (short)r;
}
__device__ __forceinline__ float bf16_to_f(short h) {
  union { uint32_t u; float f; } v;
  v.u = ((uint32_t)(uint16_t)h) << 16;
  return v.f;
}
// Split 8 floats into hi/lo bf16 fragments: f ≈ hi + lo with ~2^-18 residual
__device__ __forceinline__ void split8(const float* f, bf16x8& hi, bf16x8& lo) {
#pragma unroll
  for (int j = 0; j < 8; ++j) {
    short h = bf16_bits(f[j]);
    hi[j] = h;
    lo[j] = bf16_bits(f[j] - bf16_to_f(h));
  }
}

__global__ __launch_bounds__(THREADS)
void gnn_fused(const float* __restrict__ obs,
               const float* __restrict__ W_enc,
               const float* __restrict__ b_enc,
               const float* __restrict__ W_f,
               const float* __restrict__ b_f,
               const float* __restrict__ W_dec,
               const float* __restrict__ b_dec,
               float* __restrict__ out)
{
  // stride 132 floats: 528 B rows, 16B-aligned; A-frag reads hit <=2-way banks (free)
  __shared__ __align__(16) float f_in[BT][132];   // [local batch][128] stage-2 output
  __shared__ __align__(16) float hidn[BT][132];   // [local batch][128] stage-3 output

  const int tid  = threadIdx.x;
  const int w    = tid >> 6;     // wave 0..3
  const int l    = tid & 63;     // lane
  const int m15  = l & 15;
  const int quad = l >> 4;
  const int b0   = blockIdx.x * BT;

  // ---- stage-1 B-fragments: W_enc[k][e] columns, hi/lo, held in regs (32 VGPRs)
  bf16x8 we_hi[4], we_lo[4];
  float  benc[4];
#pragma unroll
  for (int nt = 0; nt < 4; ++nt) {
    float f[8];
#pragma unroll
    for (int j = 0; j < 8; ++j)
      f[j] = W_enc[(size_t)(quad * 8 + j) * ENCD + nt * 16 + m15];
    split8(f, we_hi[nt], we_lo[nt]);
    benc[nt] = b_enc[nt * 16 + m15];
  }

  // ================= stage 1 (enc MFMA) + stage 2 (masked mean-pool) =========
  // wave handles batches [b0 + w*8, b0 + w*8 + 8)
  // lane's A-fragment = states[b][m15][quad*8 .. quad*8+8) : contiguous in HBM
  const float* bp = obs + (size_t)(b0 + w * 8) * (NS * SS) + m15 * SS + quad * 8;
  float4 c0 = ((const float4*)bp)[0];
  float4 c1 = ((const float4*)bp)[1];
#pragma unroll
  for (int i = 0; i < 8; ++i) {
    float4 n0, n1;
    if (i < 7) {  // prefetch next batch element
      const float* np = bp + (size_t)(i + 1) * (NS * SS);
      n0 = ((const float4*)np)[0];
      n1 = ((const float4*)np)[1];
    } else { n0 = c0; n1 = c1; }

    float f[8] = {c0.x, c0.y, c0.z, c0.w, c1.x, c1.y, c1.z, c1.w};

    // flags: lanes 0..15 hold states[b][n][0]. cumprod run via ballot+ctz.
    unsigned long long bal = __ballot((l < 16) && (f[0] == 1.0f));
    int run = __builtin_ctzll(~(bal >> 1));      // # consecutive valid neighbors, 0..15
    float inv = 1.0f / fmaxf((float)run, 1.0f);  // 1/max(cnt,1)

    bf16x8 ahi, alo;
    split8(f, ahi, alo);

    const int bi = w * 8 + i;  // local batch row
#pragma unroll
    for (int nt = 0; nt < 4; ++nt) {
      f32x4 acc = {0.f, 0.f, 0.f, 0.f};
      acc = MFMA(ahi, we_hi[nt], acc);
      acc = MFMA(alo, we_hi[nt], acc);
      acc = MFMA(ahi, we_lo[nt], acc);
      // D layout: lane holds enc[n = quad*4 + r][e = nt*16 + m15]
      float s = 0.f, e0 = 0.f;
#pragma unroll
      for (int r = 0; r < 4; ++r) {
        int n = quad * 4 + r;
        float v = fmaxf(acc[r] + benc[nt], 0.f);
        if (n == 0) e0 = v;                    // agent row (quad 0, r 0)
        if (n >= 1 && n <= run) s += v;        // valid neighbor
      }
      s += __shfl_xor(s, 16, 64);              // reduce across quads
      s += __shfl_xor(s, 32, 64);
      if (quad == 0) {
        f_in[bi][nt * 16 + m15]      = e0;      // agent_enc
        f_in[bi][64 + nt * 16 + m15] = s * inv; // agg
      }
    }
    c0 = n0; c1 = n1;
  }
  __syncthreads();

  // ================= stage 3: hidden = relu(f_in @ W_f + b_f) ================
  // wave w: M-tile mt = w>>1 (16 batch rows), N-tiles hb..hb+3 (64 h columns)
  {
    const int mt = w >> 1;
    const int hb = (w & 1) * 4;

    bf16x8 fa_hi[4], fa_lo[4];
#pragma unroll
    for (int ks = 0; ks < 4; ++ks) {
      const float4* p = (const float4*)&f_in[mt * 16 + m15][ks * 32 + quad * 8];
      float4 a = p[0], b = p[1];
      float f[8] = {a.x, a.y, a.z, a.w, b.x, b.y, b.z, b.w};
      split8(f, fa_hi[ks], fa_lo[ks]);
    }

#pragma unroll
    for (int t = 0; t < 4; ++t) {
      const int h0 = (hb + t) * 16 + m15;       // output column
      f32x4 acc = {0.f, 0.f, 0.f, 0.f};
#pragma unroll
      for (int ks = 0; ks < 4; ++ks) {
        float f[8];
#pragma unroll
        for (int j = 0; j < 8; ++j)             // W_f column chunk (L1/L2 resident)
          f[j] = W_f[(size_t)(ks * 32 + quad * 8 + j) * HIDD + h0];
        bf16x8 bhi, blo;
        split8(f, bhi, blo);
        acc = MFMA(fa_hi[ks], bhi, acc);
        acc = MFMA(fa_lo[ks], bhi, acc);
        acc = MFMA(fa_hi[ks], blo, acc);
      }
      const float bfv = b_f[h0];
#pragma unroll
      for (int r = 0; r < 4; ++r)               // D: row = batch, col = h0
        hidn[mt * 16 + quad * 4 + r][h0] = fmaxf(acc[r] + bfv, 0.f);
    }
  }
  __syncthreads();

  // ================= stage 4: logits = hidden @ W_dec + b_dec ================
  if (w < 2) {                                   // waves 0,1 cover M-tiles 0,1
    bf16x8 ga_hi[4], ga_lo[4];
#pragma unroll
    for (int ks = 0; ks < 4; ++ks) {
      const float4* p = (const float4*)&hidn[w * 16 + m15][ks * 32 + quad * 8];
      float4 a = p[0], b = p[1];
      float f[8] = {a.x, a.y, a.z, a.w, b.x, b.y, b.z, b.w};
      split8(f, ga_hi[ks], ga_lo[ks]);
    }
    f32x4 acc = {0.f, 0.f, 0.f, 0.f};
#pragma unroll
    for (int ks = 0; ks < 4; ++ks) {
      float f[8];
#pragma unroll
      for (int j = 0; j < 8; ++j) {
        int k = ks * 32 + quad * 8 + j;
        f[j] = (m15 < OUTD) ? W_dec[(size_t)k * OUTD + m15] : 0.f;  // pad N 8->16
      }
      bf16x8 bhi, blo;
      split8(f, bhi, blo);
      acc = MFMA(ga_hi[ks], bhi, acc);
      acc = MFMA(ga_lo[ks], bhi, acc);
      acc = MFMA(ga_hi[ks], blo, acc);
    }
    if (m15 < OUTD) {
      const float bd = b_dec[m15];
#pragma unroll
      for (int r = 0; r < 4; ++r) {
        const int m = w * 16 + quad * 4 + r;
        out[(size_t)(b0 + m) * OUTD + m15] = acc[r] + bd;
      }
    }
  }
}

extern "C" void kernel_launch(void* const* d_in, const int* in_sizes, int n_in,
                              void* d_out, int out_size, void* d_ws, size_t ws_size,
                              hipStream_t stream) {
  (void)in_sizes; (void)n_in; (void)d_ws; (void)ws_size; (void)out_size;
  const float* obs   = (const float*)d_in[0];
  const float* W_enc = (const float*)d_in[1];
  const float* b_enc = (const float*)d_in[2];
  const float* W_f   = (const float*)d_in[3];
  const float* b_f   = (const float*)d_in[4];
  const float* W_dec = (const float*)d_in[5];
  const float* b_dec = (const float*)d_in[6];
  float* out = (float*)d_out;

  dim3 grid(NB / BT);      // 1024 blocks, exact
  dim3 block(THREADS);     // 256 threads = 4 waves
  gnn_fused<<<grid, block, 0, stream>>>(obs, W_enc, b_enc, W_f, b_f, W_dec, b_dec, out);
}

// Round 3
// 111.333 us; speedup vs baseline: 1.0912x; 1.0912x over previous
//
#include <hip/hip_runtime.h>
#include <stdint.h>

// Problem constants (fixed by the reference)
#define NB    32768   // batch
#define NS    16      // states per element
#define SS    32      // state size (K of stage 1)
#define ENCD  64      // encoder width
#define HIDD  128     // hidden width
#define OUTD  8       // output logits
#define BT    16      // batch elements per block
#define THREADS 256   // 4 waves

typedef _Float16 half8  __attribute__((ext_vector_type(8)));  // 8 f16 = 4 VGPRs
typedef __fp16   fp16x2 __attribute__((ext_vector_type(2)));  // cvt_pkrtz result type
typedef float    f32x4  __attribute__((ext_vector_type(4)));

#define MFMA(a, b, c) __builtin_amdgcn_mfma_f32_16x16x32_f16((a), (b), (c), 0, 0, 0)

// Split 8 floats into fp16 hi + lo: f = hi + lo + O(2^-20 |f|).
// v_cvt_pkrtz packs 2 floats -> 2 f16 in ONE VALU op (RTZ; lo captures the error).
__device__ __forceinline__ void split8(const float* f, half8& hi, half8& lo) {
#pragma unroll
  for (int j = 0; j < 8; j += 2) {
    fp16x2 h  = __builtin_amdgcn_cvt_pkrtz(f[j], f[j + 1]);
    float  r0 = f[j]     - (float)h[0];
    float  r1 = f[j + 1] - (float)h[1];
    fp16x2 l2 = __builtin_amdgcn_cvt_pkrtz(r0, r1);
    hi[j] = (_Float16)(float)h[0];  hi[j + 1] = (_Float16)(float)h[1];
    lo[j] = (_Float16)(float)l2[0]; lo[j + 1] = (_Float16)(float)l2[1];
  }
}

__global__ __launch_bounds__(THREADS, 6)   // cap ~85 VGPR -> 6 waves/SIMD target
void gnn_fused(const float* __restrict__ obs,
               const float* __restrict__ W_enc,
               const float* __restrict__ b_enc,
               const float* __restrict__ W_f,
               const float* __restrict__ b_f,
               const float* __restrict__ W_dec,
               const float* __restrict__ b_dec,
               float* __restrict__ out)
{
  // stride 132 floats: rows 528 B (16B-aligned), row-to-row bank shift of 4
  __shared__ __align__(16) float f_in[BT][132];   // stage-2 output [batch][128]
  __shared__ __align__(16) float hidn[BT][132];   // stage-3 output [batch][128]

  const int tid  = threadIdx.x;
  const int w    = tid >> 6;     // wave 0..3
  const int l    = tid & 63;     // lane
  const int m15  = l & 15;
  const int quad = l >> 4;
  const int b0   = blockIdx.x * BT;

  // ---- stage-1 B-fragments: W_enc[k][e] columns, hi/lo fp16, in regs (32 VGPRs)
  half8 we_hi[4], we_lo[4];
  float benc[4];
#pragma unroll
  for (int nt = 0; nt < 4; ++nt) {
    float f[8];
#pragma unroll
    for (int j = 0; j < 8; ++j)
      f[j] = W_enc[(size_t)(quad * 8 + j) * ENCD + nt * 16 + m15];
    split8(f, we_hi[nt], we_lo[nt]);
    benc[nt] = b_enc[nt * 16 + m15];
  }

  // ================= stage 1 (enc MFMA) + stage 2 (masked mean-pool) =========
  // wave handles batches [b0 + w*4, b0 + w*4 + 4)
  // lane's A-fragment = states[b][m15][quad*8 .. +8) : 32 contiguous bytes in HBM
  const float* bp = obs + (size_t)(b0 + w * 4) * (NS * SS) + m15 * SS + quad * 8;
  float4 c0 = ((const float4*)bp)[0];
  float4 c1 = ((const float4*)bp)[1];
#pragma unroll
  for (int i = 0; i < 4; ++i) {
    float4 n0, n1;
    if (i < 3) {  // prefetch next batch element
      const float* np = bp + (size_t)(i + 1) * (NS * SS);
      n0 = ((const float4*)np)[0];
      n1 = ((const float4*)np)[1];
    } else { n0 = c0; n1 = c1; }

    float f[8] = {c0.x, c0.y, c0.z, c0.w, c1.x, c1.y, c1.z, c1.w};

    // flags: lanes 0..15 hold states[b][n][0]; cumprod run length via ballot+ctz
    unsigned long long bal = __ballot((l < 16) && (f[0] == 1.0f));
    int run = __builtin_ctzll(~(bal >> 1));      // consecutive valid neighbors, 0..15
    float inv = 1.0f / fmaxf((float)run, 1.0f);

    half8 ahi, alo;
    split8(f, ahi, alo);

    const int bi = w * 4 + i;  // local batch row
#pragma unroll
    for (int nt = 0; nt < 4; ++nt) {
      f32x4 acc = {0.f, 0.f, 0.f, 0.f};
      acc = MFMA(ahi, we_hi[nt], acc);
      acc = MFMA(alo, we_hi[nt], acc);
      acc = MFMA(ahi, we_lo[nt], acc);
      // D layout: lane holds enc[n = quad*4 + r][e = nt*16 + m15]
      float s = 0.f, e0 = 0.f;
#pragma unroll
      for (int r = 0; r < 4; ++r) {
        int n = quad * 4 + r;
        float v = fmaxf(acc[r] + benc[nt], 0.f);
        if (n == 0) e0 = v;                    // agent row
        if (n >= 1 && n <= run) s += v;        // valid neighbor
      }
      s += __shfl_xor(s, 16, 64);              // reduce across quads
      s += __shfl_xor(s, 32, 64);
      if (quad == 0) {
        f_in[bi][nt * 16 + m15]      = e0;      // agent_enc
        f_in[bi][64 + nt * 16 + m15] = s * inv; // agg
      }
    }
    c0 = n0; c1 = n1;
  }
  __syncthreads();

  // ================= stage 3: hidden = relu(f_in @ W_f + b_f) ================
  // single 16-row M-tile; wave w covers N-tiles 2w, 2w+1 (32 of 128 h-columns)
  {
    half8 fa_hi[4], fa_lo[4];
#pragma unroll
    for (int ks = 0; ks < 4; ++ks) {
      const float4* p = (const float4*)&f_in[m15][ks * 32 + quad * 8];
      float4 a = p[0], b = p[1];
      float f[8] = {a.x, a.y, a.z, a.w, b.x, b.y, b.z, b.w};
      split8(f, fa_hi[ks], fa_lo[ks]);
    }

#pragma unroll
    for (int tt = 0; tt < 2; ++tt) {
      const int h0 = (w * 2 + tt) * 16 + m15;   // output column
      f32x4 acc = {0.f, 0.f, 0.f, 0.f};
#pragma unroll
      for (int ks = 0; ks < 4; ++ks) {
        float f[8];
#pragma unroll
        for (int j = 0; j < 8; ++j)             // W_f column chunk (L1/L2 resident)
          f[j] = W_f[(size_t)(ks * 32 + quad * 8 + j) * HIDD + h0];
        half8 bhi, blo;
        split8(f, bhi, blo);
        acc = MFMA(fa_hi[ks], bhi, acc);
        acc = MFMA(fa_lo[ks], bhi, acc);
        acc = MFMA(fa_hi[ks], blo, acc);
      }
      const float bfv = b_f[h0];
#pragma unroll
      for (int r = 0; r < 4; ++r)               // D: row = batch, col = h0
        hidn[quad * 4 + r][h0] = fmaxf(acc[r] + bfv, 0.f);
    }
  }
  __syncthreads();

  // ================= stage 4: logits = hidden @ W_dec + b_dec ================
  if (w == 0) {                                  // one 16-row M-tile
    half8 ga_hi[4], ga_lo[4];
#pragma unroll
    for (int ks = 0; ks < 4; ++ks) {
      const float4* p = (const float4*)&hidn[m15][ks * 32 + quad * 8];
      float4 a = p[0], b = p[1];
      float f[8] = {a.x, a.y, a.z, a.w, b.x, b.y, b.z, b.w};
      split8(f, ga_hi[ks], ga_lo[ks]);
    }
    f32x4 acc = {0.f, 0.f, 0.f, 0.f};
#pragma unroll
    for (int ks = 0; ks < 4; ++ks) {
      float f[8];
#pragma unroll
      for (int j = 0; j < 8; ++j) {
        int k = ks * 32 + quad * 8 + j;
        f[j] = (m15 < OUTD) ? W_dec[(size_t)k * OUTD + m15] : 0.f;  // pad N 8->16
      }
      half8 bhi, blo;
      split8(f, bhi, blo);
      acc = MFMA(ga_hi[ks], bhi, acc);
      acc = MFMA(ga_lo[ks], bhi, acc);
      acc = MFMA(ga_hi[ks], blo, acc);
    }
    if (m15 < OUTD) {
      const float bd = b_dec[m15];
#pragma unroll
      for (int r = 0; r < 4; ++r) {
        const int m = quad * 4 + r;
        out[(size_t)(b0 + m) * OUTD + m15] = acc[r] + bd;
      }
    }
  }
}

extern "C" void kernel_launch(void* const* d_in, const int* in_sizes, int n_in,
                              void* d_out, int out_size, void* d_ws, size_t ws_size,
                              hipStream_t stream) {
  (void)in_sizes; (void)n_in; (void)d_ws; (void)ws_size; (void)out_size;
  const float* obs   = (const float*)d_in[0];
  const float* W_enc = (const float*)d_in[1];
  const float* b_enc = (const float*)d_in[2];
  const float* W_f   = (const float*)d_in[3];
  const float* b_f   = (const float*)d_in[4];
  const float* W_dec = (const float*)d_in[5];
  const float* b_dec = (const float*)d_in[6];
  float* out = (float*)d_out;

  dim3 grid(NB / BT);      // 2048 blocks
  dim3 block(THREADS);     // 256 threads = 4 waves
  gnn_fused<<<grid, block, 0, stream>>>(obs, W_enc, b_enc, W_f, b_f, W_dec, b_dec, out);
}